// Round 4
// baseline (914.494 us; speedup 1.0000x reference)
//
#include <hip/hip_runtime.h>

#define AB 513
#define TD 263169  // 513*513

typedef float f4 __attribute__((ext_vector_type(4)));
#define GAS __attribute__((address_space(1)))
#define LAS __attribute__((address_space(3)))

// ---------------------------------------------------------------------------
// Kernel 1: both modalities. Blocks 0..63 = vision bt, 64..127 = audio bt.
// ---------------------------------------------------------------------------
__global__ __launch_bounds__(256) void unimodal_kernel(
    const float* __restrict__ vx, const float* __restrict__ ax,
    const float* __restrict__ vw1, const float* __restrict__ vb1,
    const float* __restrict__ vw2, const float* __restrict__ vb2,
    const float* __restrict__ aw1, const float* __restrict__ ab1,
    const float* __restrict__ aw2, const float* __restrict__ ab2,
    float* __restrict__ aTout, float* __restrict__ bTout)
{
    const int isA = (blockIdx.x >= 64);
    const int bt = blockIdx.x & 63;
    const float* x  = isA ? ax  : vx;
    const float* w1 = isA ? aw1 : vw1;
    const float* b1 = isA ? ab1 : vb1;
    const float* w2 = isA ? aw2 : vw2;
    const float* b2 = isA ? ab2 : vb2;
    float* outT = isA ? bTout : aTout;
    const int D = isA ? 512 : 768;

    __shared__ float p_sh[768];
    __shared__ float h_sh[512];
    const int tid = threadIdx.x;
    const int lane = tid & 63, wid = tid >> 6;

    const int nd4 = D >> 2;
    for (int d4 = tid; d4 < nd4; d4 += 256) {
        f4 s = {0.f, 0.f, 0.f, 0.f};
        const float* xp = x + (size_t)bt * 64 * D + d4 * 4;
        for (int ss = 0; ss < 64; ++ss) {
            f4 v = *(const f4*)(xp + (size_t)ss * D);
            s += v;
        }
        *(f4*)&p_sh[d4 * 4] = s * 0.015625f;
    }
    __syncthreads();

    const int nit = D >> 8;
    for (int h0 = wid * 8; h0 < 512; h0 += 32) {
        float s[8];
        #pragma unroll
        for (int k = 0; k < 8; ++k) s[k] = 0.f;
        for (int it = 0; it < nit; ++it) {
            const int d = it * 256 + lane * 4;
            const f4 p = *(const f4*)&p_sh[d];
            #pragma unroll
            for (int k = 0; k < 8; ++k) {
                const f4 w = *(const f4*)&w1[(size_t)(h0 + k) * D + d];
                s[k] = fmaf(w[0], p[0], fmaf(w[1], p[1],
                       fmaf(w[2], p[2], fmaf(w[3], p[3], s[k]))));
            }
        }
        #pragma unroll
        for (int k = 0; k < 8; ++k) {
            float v = s[k];
            #pragma unroll
            for (int m = 1; m < 64; m <<= 1) v += __shfl_xor(v, m, 64);
            if (lane == 0) h_sh[h0 + k] = fmaxf(v + b1[h0 + k], 0.f);
        }
    }
    __syncthreads();

    for (int h0 = wid * 8; h0 < 512; h0 += 32) {
        float s[8];
        #pragma unroll
        for (int k = 0; k < 8; ++k) s[k] = 0.f;
        for (int it = 0; it < 2; ++it) {
            const int d = it * 256 + lane * 4;
            const f4 p = *(const f4*)&h_sh[d];
            #pragma unroll
            for (int k = 0; k < 8; ++k) {
                const f4 w = *(const f4*)&w2[(size_t)(h0 + k) * 512 + d];
                s[k] = fmaf(w[0], p[0], fmaf(w[1], p[1],
                       fmaf(w[2], p[2], fmaf(w[3], p[3], s[k]))));
            }
        }
        #pragma unroll
        for (int k = 0; k < 8; ++k) {
            float v = s[k];
            #pragma unroll
            for (int m = 1; m < 64; m <<= 1) v += __shfl_xor(v, m, 64);
            if (lane == 0) outT[(h0 + k) * 64 + bt] = v + b2[h0 + k];
        }
    }
    if (tid == 0) outT[512 * 64 + bt] = 1.0f;
}

// ---------------------------------------------------------------------------
// Kernel 2: bilinear h[bt,o] = relu( a^T W_o b + fb1[o] ).
// Grid 512 x 512 thr; block does o = {2bx, 2bx+1} sequentially.
// NEW layout: tid = e (0..511); wave covers a 64-e slice; acc[64] over bt.
// Per dd: 1 ds_read_b32 (W, 64 distinct elems/instr) + lane-uniform a-row
// (s_load, scalar pipe) + 64 independent FMAs. W double-buffered in LDS via
// width-16 global_load_lds; prefetch of next-o chunk 0 hides under epilogue.
// ---------------------------------------------------------------------------
__global__ __launch_bounds__(512, 2) void bilinear_kernel(
    const float* __restrict__ fw1,  // (1024, 263169)
    const float* __restrict__ fb1,  // (1024)
    const float* __restrict__ aT,   // (513, 64)
    const float* __restrict__ bT,   // (513, 64)
    float* __restrict__ hbuf)       // (64, 1024)
{
    __shared__ float wbuf[2][8 * 512];
    __shared__ float red[8][65];  // padded: conflict-free column read
    const int tid = threadIdx.x;
    const int lane = tid & 63, wid = tid >> 6;
    const int ew = tid;          // this thread's e index
    const int bt0 = wid * 8;

    #define STAGE(buf, Wc)                                                     \
        do {                                                                   \
            _Pragma("unroll")                                                  \
            for (int s_ = 0; s_ < 2; ++s_) {                                   \
                const int row_ = s_ * 4 + (tid >> 7);                          \
                const int col_ = (tid & 127) * 4;                              \
                __builtin_amdgcn_global_load_lds(                              \
                    (const GAS uint32_t*)(const void*)((Wc) + (size_t)row_ * AB + col_), \
                    (LAS uint32_t*)(void*)&wbuf[buf][row_ * 512 + col_], 16, 0, 0); \
            }                                                                  \
        } while (0)

    const int o0 = blockIdx.x * 2;
    STAGE(0, fw1 + (size_t)o0 * TD);

    for (int ooi = 0; ooi < 2; ++ooi) {
        const int o = o0 + ooi;
        const float* __restrict__ W = fw1 + (size_t)o * TD;

        float acc[64];
        #pragma unroll
        for (int j = 0; j < 64; ++j) acc[j] = 0.f;

        __syncthreads();  // chunk-0 staged; LDS free from previous epilogue

        for (int c = 0; c < 64; ++c) {
            const int cur = c & 1;
            if (c < 63) STAGE(cur ^ 1, W + (size_t)(c + 1) * 8 * AB);
            else if (ooi == 0) STAGE(0, fw1 + (size_t)(o + 1) * TD);

            #pragma unroll
            for (int dd = 0; dd < 8; ++dd) {
                const float w = wbuf[cur][dd * 512 + ew];
                const float* __restrict__ arow = aT + (size_t)(c * 8 + dd) * 64;
                #pragma unroll
                for (int q = 0; q < 16; ++q) {
                    const f4 av = *(const f4*)(arow + q * 4);  // uniform -> s_load
                    acc[q * 4 + 0] = fmaf(w, av[0], acc[q * 4 + 0]);
                    acc[q * 4 + 1] = fmaf(w, av[1], acc[q * 4 + 1]);
                    acc[q * 4 + 2] = fmaf(w, av[2], acc[q * 4 + 2]);
                    acc[q * 4 + 3] = fmaf(w, av[3], acc[q * 4 + 3]);
                }
            }
            __syncthreads();
        }

        // d = 512 row (a == 1): acc[j] += W[512, ew]
        const float wlast = W[(size_t)512 * AB + ew];
        #pragma unroll
        for (int j = 0; j < 64; ++j) acc[j] += wlast;

        // e = 512 col (b == 1) for this wave's 8 bt: t[rr] = sum_d a[d,bt]*W[d,512]
        float t[8];
        #pragma unroll
        for (int j = 0; j < 8; ++j) t[j] = 0.f;
        #pragma unroll
        for (int k = 0; k < 8; ++k) {
            const int d = k * 64 + lane;
            const float wv = W[(size_t)d * AB + 512];
            const float* ar = aT + (size_t)d * 64 + bt0;
            const f4 a01 = *(const f4*)ar;
            const f4 a23 = *(const f4*)(ar + 4);
            t[0] = fmaf(a01[0], wv, t[0]);
            t[1] = fmaf(a01[1], wv, t[1]);
            t[2] = fmaf(a01[2], wv, t[2]);
            t[3] = fmaf(a01[3], wv, t[3]);
            t[4] = fmaf(a23[0], wv, t[4]);
            t[5] = fmaf(a23[1], wv, t[5]);
            t[6] = fmaf(a23[2], wv, t[6]);
            t[7] = fmaf(a23[3], wv, t[7]);
        }
        if (lane == 0) {
            const float wl = W[(size_t)512 * AB + 512];  // d=512,e=512 (a=b=1)
            #pragma unroll
            for (int j = 0; j < 8; ++j) t[j] += wl;
        }
        #pragma unroll
        for (int j = 0; j < 8; ++j) {
            float v = t[j];
            #pragma unroll
            for (int m = 1; m < 64; m <<= 1) v += __shfl_xor(v, m, 64);
            t[j] = v;
        }

        // b-scale + per-wave lane reduction, 8 bt at a time
        const float* __restrict__ brow = bT + (size_t)ew * 64;
        #pragma unroll
        for (int p = 0; p < 8; ++p) {
            const f4 b01 = *(const f4*)(brow + p * 8);
            const f4 b23 = *(const f4*)(brow + p * 8 + 4);
            float s[8];
            s[0] = acc[p * 8 + 0] * b01[0];
            s[1] = acc[p * 8 + 1] * b01[1];
            s[2] = acc[p * 8 + 2] * b01[2];
            s[3] = acc[p * 8 + 3] * b01[3];
            s[4] = acc[p * 8 + 4] * b23[0];
            s[5] = acc[p * 8 + 5] * b23[1];
            s[6] = acc[p * 8 + 6] * b23[2];
            s[7] = acc[p * 8 + 7] * b23[3];
            #pragma unroll
            for (int r = 0; r < 8; ++r) {
                float v = s[r];
                #pragma unroll
                for (int m = 1; m < 64; m <<= 1) v += __shfl_xor(v, m, 64);
                s[r] = v;
            }
            if (lane == 0) {
                #pragma unroll
                for (int r = 0; r < 8; ++r) red[wid][p * 8 + r] = s[r];
            }
        }
        __syncthreads();

        // final: wave wid folds 8 wave-partials for bt = bt0..bt0+7
        #pragma unroll
        for (int rr = 0; rr < 8; ++rr) {
            const int bt = bt0 + rr;
            float v = (lane < 8) ? red[lane][bt] : 0.f;
            v += __shfl_xor(v, 1, 64);
            v += __shfl_xor(v, 2, 64);
            v += __shfl_xor(v, 4, 64);
            if (lane == 0)
                hbuf[(size_t)bt * 1024 + o] = fmaxf(v + t[rr] + fb1[o], 0.f);
        }
        // red/wbuf reuse protected by top-of-loop __syncthreads
    }
    #undef STAGE
}

// ---------------------------------------------------------------------------
// Kernel 3a: fused[bt, f] = h[bt, :] @ fw2[f, :] + fb2[f]
// ---------------------------------------------------------------------------
__global__ __launch_bounds__(256) void fuse2_kernel(
    const float* __restrict__ hbuf,  // (64, 1024)
    const float* __restrict__ fw2,   // (512, 1024)
    const float* __restrict__ fb2,   // (512)
    float* __restrict__ fused)       // (64, 512)
{
    __shared__ float h_sh[1024];
    const int bt = blockIdx.x, tid = threadIdx.x;
    const int lane = tid & 63, wid = tid >> 6;
    *(f4*)&h_sh[tid * 4] = *(const f4*)&hbuf[bt * 1024 + tid * 4];
    __syncthreads();
    for (int f0 = wid * 8; f0 < 512; f0 += 32) {
        float s[8];
        #pragma unroll
        for (int k = 0; k < 8; ++k) s[k] = 0.f;
        #pragma unroll
        for (int it = 0; it < 4; ++it) {
            const int d = it * 256 + lane * 4;
            const f4 p = *(const f4*)&h_sh[d];
            #pragma unroll
            for (int k = 0; k < 8; ++k) {
                const f4 w = *(const f4*)&fw2[(size_t)(f0 + k) * 1024 + d];
                s[k] = fmaf(w[0], p[0], fmaf(w[1], p[1],
                       fmaf(w[2], p[2], fmaf(w[3], p[3], s[k]))));
            }
        }
        #pragma unroll
        for (int k = 0; k < 8; ++k) {
            float v = s[k];
            #pragma unroll
            for (int m = 1; m < 64; m <<= 1) v += __shfl_xor(v, m, 64);
            if (lane == 0) fused[bt * 512 + f0 + k] = v + fb2[f0 + k];
        }
    }
}

// ---------------------------------------------------------------------------
// Kernel 3b: LIF over time. 1024 independent (b, d) chains, T = 32.
// ---------------------------------------------------------------------------
__global__ __launch_bounds__(256) void lif_kernel(
    const float* __restrict__ fused,  // (2, 32, 512)
    float* __restrict__ out)          // (2, 32, 512)
{
    const int idx = blockIdx.x * 256 + threadIdx.x;
    if (idx >= 1024) return;
    const int b = idx >> 9, dd = idx & 511;
    float mem = 0.f;
    for (int t = 0; t < 32; ++t) {
        const size_t off = ((size_t)(b * 32 + t) * 512) + dd;
        mem = 0.9f * mem + fused[off];
        const float s = (mem >= 1.0f) ? 1.0f : 0.0f;
        out[off] = s;
        mem -= s;
    }
}

// ---------------------------------------------------------------------------
extern "C" void kernel_launch(void* const* d_in, const int* in_sizes, int n_in,
                              void* d_out, int out_size, void* d_ws, size_t ws_size,
                              hipStream_t stream) {
    const float* vision = (const float*)d_in[0];
    const float* audio  = (const float*)d_in[1];
    const float* vw1 = (const float*)d_in[2];
    const float* vb1 = (const float*)d_in[3];
    const float* vw2 = (const float*)d_in[4];
    const float* vb2 = (const float*)d_in[5];
    const float* aw1 = (const float*)d_in[6];
    const float* ab1 = (const float*)d_in[7];
    const float* aw2 = (const float*)d_in[8];
    const float* ab2 = (const float*)d_in[9];
    const float* fw1 = (const float*)d_in[10];
    const float* fb1 = (const float*)d_in[11];
    const float* fw2 = (const float*)d_in[12];
    const float* fb2 = (const float*)d_in[13];
    float* out = (float*)d_out;

    float* ws    = (float*)d_ws;
    float* aT    = ws;                 // 513*64
    float* bT    = aT + AB * 64;       // 513*64
    float* hbuf  = bT + AB * 64;       // 64*1024
    float* fused = hbuf + 64 * 1024;   // 64*512

    unimodal_kernel<<<128, 256, 0, stream>>>(vision, audio,
        vw1, vb1, vw2, vb2, aw1, ab1, aw2, ab2, aT, bT);
    bilinear_kernel<<<512, 512, 0, stream>>>(fw1, fb1, aT, bT, hbuf);
    fuse2_kernel<<<64, 256, 0, stream>>>(hbuf, fw2, fb2, fused);
    lif_kernel<<<4, 256, 0, stream>>>(fused, out);
}

// Round 5
// 868.008 us; speedup vs baseline: 1.0536x; 1.0536x over previous
//
#include <hip/hip_runtime.h>

#define AB 513
#define TD 263169  // 513*513

typedef float f4 __attribute__((ext_vector_type(4)));

// ---------------------------------------------------------------------------
// Kernel 1: both modalities. Blocks 0..63 = vision bt, 64..127 = audio bt.
// ---------------------------------------------------------------------------
__global__ __launch_bounds__(256) void unimodal_kernel(
    const float* __restrict__ vx, const float* __restrict__ ax,
    const float* __restrict__ vw1, const float* __restrict__ vb1,
    const float* __restrict__ vw2, const float* __restrict__ vb2,
    const float* __restrict__ aw1, const float* __restrict__ ab1,
    const float* __restrict__ aw2, const float* __restrict__ ab2,
    float* __restrict__ aTout, float* __restrict__ bTout)
{
    const int isA = (blockIdx.x >= 64);
    const int bt = blockIdx.x & 63;
    const float* x  = isA ? ax  : vx;
    const float* w1 = isA ? aw1 : vw1;
    const float* b1 = isA ? ab1 : vb1;
    const float* w2 = isA ? aw2 : vw2;
    const float* b2 = isA ? ab2 : vb2;
    float* outT = isA ? bTout : aTout;
    const int D = isA ? 512 : 768;

    __shared__ float p_sh[768];
    __shared__ float h_sh[512];
    const int tid = threadIdx.x;
    const int lane = tid & 63, wid = tid >> 6;

    // pool: 4 partial accumulators -> 16+ loads in flight (breaks the
    // 64-deep serial HBM latency chain)
    const int nd4 = D >> 2;
    for (int d4 = tid; d4 < nd4; d4 += 256) {
        f4 s0 = {0.f, 0.f, 0.f, 0.f}, s1 = s0, s2 = s0, s3 = s0;
        const float* xp = x + (size_t)bt * 64 * D + d4 * 4;
        #pragma unroll 4
        for (int ss = 0; ss < 64; ss += 4) {
            s0 += *(const f4*)(xp + (size_t)ss * D);
            s1 += *(const f4*)(xp + (size_t)(ss + 1) * D);
            s2 += *(const f4*)(xp + (size_t)(ss + 2) * D);
            s3 += *(const f4*)(xp + (size_t)(ss + 3) * D);
        }
        const f4 s = (s0 + s1) + (s2 + s3);
        *(f4*)&p_sh[d4 * 4] = s * 0.015625f;
    }
    __syncthreads();

    const int nit = D >> 8;
    for (int h0 = wid * 8; h0 < 512; h0 += 32) {
        float s[8];
        #pragma unroll
        for (int k = 0; k < 8; ++k) s[k] = 0.f;
        for (int it = 0; it < nit; ++it) {
            const int d = it * 256 + lane * 4;
            const f4 p = *(const f4*)&p_sh[d];
            #pragma unroll
            for (int k = 0; k < 8; ++k) {
                const f4 w = *(const f4*)&w1[(size_t)(h0 + k) * D + d];
                s[k] = fmaf(w[0], p[0], fmaf(w[1], p[1],
                       fmaf(w[2], p[2], fmaf(w[3], p[3], s[k]))));
            }
        }
        #pragma unroll
        for (int k = 0; k < 8; ++k) {
            float v = s[k];
            #pragma unroll
            for (int m = 1; m < 64; m <<= 1) v += __shfl_xor(v, m, 64);
            if (lane == 0) h_sh[h0 + k] = fmaxf(v + b1[h0 + k], 0.f);
        }
    }
    __syncthreads();

    for (int h0 = wid * 8; h0 < 512; h0 += 32) {
        float s[8];
        #pragma unroll
        for (int k = 0; k < 8; ++k) s[k] = 0.f;
        for (int it = 0; it < 2; ++it) {
            const int d = it * 256 + lane * 4;
            const f4 p = *(const f4*)&h_sh[d];
            #pragma unroll
            for (int k = 0; k < 8; ++k) {
                const f4 w = *(const f4*)&w2[(size_t)(h0 + k) * 512 + d];
                s[k] = fmaf(w[0], p[0], fmaf(w[1], p[1],
                       fmaf(w[2], p[2], fmaf(w[3], p[3], s[k]))));
            }
        }
        #pragma unroll
        for (int k = 0; k < 8; ++k) {
            float v = s[k];
            #pragma unroll
            for (int m = 1; m < 64; m <<= 1) v += __shfl_xor(v, m, 64);
            if (lane == 0) outT[(h0 + k) * 64 + bt] = v + b2[h0 + k];
        }
    }
    if (tid == 0) outT[512 * 64 + bt] = 1.0f;
}

// ---------------------------------------------------------------------------
// Kernel 2: bilinear h[bt,o] = relu( a^T W_o b + fb1[o] ).
// Grid 1024 x 512 thr; one block per o. Wave = bt-group of 8; each thread
// owns e in {4*lane..+3} U {256+4*lane..+3}; acc[8e][8bt] in VGPRs.
// W is loaded global->VGPR directly (each W element used by exactly one
// thread; 8-wave duplication hits L1). a-row is wave-uniform, L2-hot.
// Register double-buffer depth 2; NO LDS, NO barriers. Rows 512 of W/aT
// exist, so the d+1 prefetch needs no guard.
// ---------------------------------------------------------------------------
__global__ __launch_bounds__(512, 2) void bilinear_kernel(
    const float* __restrict__ fw1,  // (1024, 263169)
    const float* __restrict__ fb1,  // (1024)
    const float* __restrict__ aT,   // (513, 64)
    const float* __restrict__ bT,   // (513, 64)
    float* __restrict__ hbuf)       // (64, 1024)
{
    const int tid = threadIdx.x;
    const int lane = tid & 63, w = tid >> 6;
    const int o = blockIdx.x;
    const float* __restrict__ W = fw1 + (size_t)o * TD;
    const int e0 = lane * 4;   // quads at e0 and e0+256
    const int bt0 = w * 8;

    float acc[8][8];  // [e-sub][bt]
    #pragma unroll
    for (int i = 0; i < 8; ++i)
        #pragma unroll
        for (int j = 0; j < 8; ++j) acc[i][j] = 0.f;

    f4 wA[2], wB[2], aA[2], aB[2];
    const float* pW = W + e0;
    const float* pA = aT + bt0;

    wA[0] = *(const f4*)(pW);
    wB[0] = *(const f4*)(pW + 256);
    aA[0] = *(const f4*)(pA);
    aB[0] = *(const f4*)(pA + 4);

    #pragma unroll 2
    for (int d = 0; d < 512; ++d) {
        const int cur = d & 1, nxt = cur ^ 1;
        const float* pWn = pW + (size_t)(d + 1) * AB;
        const float* pAn = pA + (size_t)(d + 1) * 64;
        wA[nxt] = *(const f4*)(pWn);
        wB[nxt] = *(const f4*)(pWn + 256);
        aA[nxt] = *(const f4*)(pAn);
        aB[nxt] = *(const f4*)(pAn + 4);
        #pragma unroll
        for (int j = 0; j < 4; ++j) {
            #pragma unroll
            for (int i = 0; i < 4; ++i) {
                acc[i][j]         = fmaf(wA[cur][i], aA[cur][j], acc[i][j]);
                acc[i + 4][j]     = fmaf(wB[cur][i], aA[cur][j], acc[i + 4][j]);
                acc[i][j + 4]     = fmaf(wA[cur][i], aB[cur][j], acc[i][j + 4]);
                acc[i + 4][j + 4] = fmaf(wB[cur][i], aB[cur][j], acc[i + 4][j + 4]);
            }
        }
    }

    // d = 512 row (a == 1): acc[i][*] += W[512, e_i]
    {
        const f4 r0 = *(const f4*)(W + (size_t)512 * AB + e0);
        const f4 r1 = *(const f4*)(W + (size_t)512 * AB + e0 + 256);
        #pragma unroll
        for (int j = 0; j < 8; ++j)
            #pragma unroll
            for (int i = 0; i < 4; ++i) {
                acc[i][j] += r0[i];
                acc[i + 4][j] += r1[i];
            }
    }

    // y[j] = sum over this thread's e of acc * b[e, bt0+j]
    float y[8];
    #pragma unroll
    for (int j = 0; j < 8; ++j) y[j] = 0.f;
    #pragma unroll
    for (int i = 0; i < 4; ++i) {
        const float* br0 = bT + (size_t)(e0 + i) * 64 + bt0;
        const float* br1 = bT + (size_t)(256 + e0 + i) * 64 + bt0;
        const f4 b0a = *(const f4*)br0, b0b = *(const f4*)(br0 + 4);
        const f4 b1a = *(const f4*)br1, b1b = *(const f4*)(br1 + 4);
        #pragma unroll
        for (int j = 0; j < 4; ++j) {
            y[j]     = fmaf(acc[i][j],     b0a[j], y[j]);
            y[j]     = fmaf(acc[i + 4][j], b1a[j], y[j]);
            y[j + 4] = fmaf(acc[i][j + 4],     b0b[j], y[j + 4]);
            y[j + 4] = fmaf(acc[i + 4][j + 4], b1b[j], y[j + 4]);
        }
    }

    // e = 512 column (b == 1): y[j] += sum_d a[d, bt0+j] * W[d, 512]
    #pragma unroll
    for (int k = 0; k < 8; ++k) {
        const int d = k * 64 + lane;
        const float wv = W[(size_t)d * AB + 512];
        const float* ar = aT + (size_t)d * 64 + bt0;
        const f4 a0 = *(const f4*)ar, a1 = *(const f4*)(ar + 4);
        #pragma unroll
        for (int j = 0; j < 4; ++j) {
            y[j]     = fmaf(a0[j], wv, y[j]);
            y[j + 4] = fmaf(a1[j], wv, y[j + 4]);
        }
    }
    {   // d = 512, e = 512 corner (a = b = 1), add on lane 0 only
        const float wc = (lane == 0) ? W[(size_t)512 * AB + 512] : 0.f;
        #pragma unroll
        for (int j = 0; j < 8; ++j) y[j] += wc;
    }

    // reduce across 64 lanes (all e), then bias + relu + store (per-wave)
    #pragma unroll
    for (int j = 0; j < 8; ++j) {
        float v = y[j];
        #pragma unroll
        for (int m = 1; m < 64; m <<= 1) v += __shfl_xor(v, m, 64);
        y[j] = v;
    }
    if (lane == 0) {
        const float bias = fb1[o];
        #pragma unroll
        for (int j = 0; j < 8; ++j)
            hbuf[(size_t)(bt0 + j) * 1024 + o] = fmaxf(y[j] + bias, 0.f);
    }
}

// ---------------------------------------------------------------------------
// Kernel 3a: fused[bt, f] = h[bt, :] @ fw2[f, :] + fb2[f]
// ---------------------------------------------------------------------------
__global__ __launch_bounds__(256) void fuse2_kernel(
    const float* __restrict__ hbuf,  // (64, 1024)
    const float* __restrict__ fw2,   // (512, 1024)
    const float* __restrict__ fb2,   // (512)
    float* __restrict__ fused)       // (64, 512)
{
    __shared__ float h_sh[1024];
    const int bt = blockIdx.x, tid = threadIdx.x;
    const int lane = tid & 63, wid = tid >> 6;
    *(f4*)&h_sh[tid * 4] = *(const f4*)&hbuf[bt * 1024 + tid * 4];
    __syncthreads();
    for (int f0 = wid * 8; f0 < 512; f0 += 32) {
        float s[8];
        #pragma unroll
        for (int k = 0; k < 8; ++k) s[k] = 0.f;
        #pragma unroll
        for (int it = 0; it < 4; ++it) {
            const int d = it * 256 + lane * 4;
            const f4 p = *(const f4*)&h_sh[d];
            #pragma unroll
            for (int k = 0; k < 8; ++k) {
                const f4 w = *(const f4*)&fw2[(size_t)(f0 + k) * 1024 + d];
                s[k] = fmaf(w[0], p[0], fmaf(w[1], p[1],
                       fmaf(w[2], p[2], fmaf(w[3], p[3], s[k]))));
            }
        }
        #pragma unroll
        for (int k = 0; k < 8; ++k) {
            float v = s[k];
            #pragma unroll
            for (int m = 1; m < 64; m <<= 1) v += __shfl_xor(v, m, 64);
            if (lane == 0) fused[bt * 512 + f0 + k] = v + fb2[f0 + k];
        }
    }
}

// ---------------------------------------------------------------------------
// Kernel 3b: LIF over time. 1024 independent (b, d) chains, T = 32.
// ---------------------------------------------------------------------------
__global__ __launch_bounds__(256) void lif_kernel(
    const float* __restrict__ fused,  // (2, 32, 512)
    float* __restrict__ out)          // (2, 32, 512)
{
    const int idx = blockIdx.x * 256 + threadIdx.x;
    if (idx >= 1024) return;
    const int b = idx >> 9, dd = idx & 511;
    float mem = 0.f;
    for (int t = 0; t < 32; ++t) {
        const size_t off = ((size_t)(b * 32 + t) * 512) + dd;
        mem = 0.9f * mem + fused[off];
        const float s = (mem >= 1.0f) ? 1.0f : 0.0f;
        out[off] = s;
        mem -= s;
    }
}

// ---------------------------------------------------------------------------
extern "C" void kernel_launch(void* const* d_in, const int* in_sizes, int n_in,
                              void* d_out, int out_size, void* d_ws, size_t ws_size,
                              hipStream_t stream) {
    const float* vision = (const float*)d_in[0];
    const float* audio  = (const float*)d_in[1];
    const float* vw1 = (const float*)d_in[2];
    const float* vb1 = (const float*)d_in[3];
    const float* vw2 = (const float*)d_in[4];
    const float* vb2 = (const float*)d_in[5];
    const float* aw1 = (const float*)d_in[6];
    const float* ab1 = (const float*)d_in[7];
    const float* aw2 = (const float*)d_in[8];
    const float* ab2 = (const float*)d_in[9];
    const float* fw1 = (const float*)d_in[10];
    const float* fb1 = (const float*)d_in[11];
    const float* fw2 = (const float*)d_in[12];
    const float* fb2 = (const float*)d_in[13];
    float* out = (float*)d_out;

    float* ws    = (float*)d_ws;
    float* aT    = ws;                 // 513*64
    float* bT    = aT + AB * 64;       // 513*64
    float* hbuf  = bT + AB * 64;       // 64*1024
    float* fused = hbuf + 64 * 1024;   // 64*512

    unimodal_kernel<<<128, 256, 0, stream>>>(vision, audio,
        vw1, vb1, vw2, vb2, aw1, ab1, aw2, ab2, aT, bT);
    bilinear_kernel<<<1024, 512, 0, stream>>>(fw1, fb1, aT, bT, hbuf);
    fuse2_kernel<<<64, 256, 0, stream>>>(hbuf, fw2, fb2, fused);
    lif_kernel<<<4, 256, 0, stream>>>(fused, out);
}

// Round 6
// 614.424 us; speedup vs baseline: 1.4884x; 1.4127x over previous
//
#include <hip/hip_runtime.h>

#define AB 513
#define TD 263169  // 513*513

typedef float f4 __attribute__((ext_vector_type(4)));
#define GAS __attribute__((address_space(1)))
#define LAS __attribute__((address_space(3)))

// ---------------------------------------------------------------------------
// Kernel 1: both modalities. Blocks 0..63 = vision bt, 64..127 = audio bt.
// ---------------------------------------------------------------------------
__global__ __launch_bounds__(256) void unimodal_kernel(
    const float* __restrict__ vx, const float* __restrict__ ax,
    const float* __restrict__ vw1, const float* __restrict__ vb1,
    const float* __restrict__ vw2, const float* __restrict__ vb2,
    const float* __restrict__ aw1, const float* __restrict__ ab1,
    const float* __restrict__ aw2, const float* __restrict__ ab2,
    float* __restrict__ aTout, float* __restrict__ bTout)
{
    const int isA = (blockIdx.x >= 64);
    const int bt = blockIdx.x & 63;
    const float* x  = isA ? ax  : vx;
    const float* w1 = isA ? aw1 : vw1;
    const float* b1 = isA ? ab1 : vb1;
    const float* w2 = isA ? aw2 : vw2;
    const float* b2 = isA ? ab2 : vb2;
    float* outT = isA ? bTout : aTout;
    const int D = isA ? 512 : 768;

    __shared__ float p_sh[768];
    __shared__ float h_sh[512];
    const int tid = threadIdx.x;
    const int lane = tid & 63, wid = tid >> 6;

    const int nd4 = D >> 2;
    for (int d4 = tid; d4 < nd4; d4 += 256) {
        f4 s0 = {0.f, 0.f, 0.f, 0.f}, s1 = s0, s2 = s0, s3 = s0;
        const float* xp = x + (size_t)bt * 64 * D + d4 * 4;
        #pragma unroll 4
        for (int ss = 0; ss < 64; ss += 4) {
            s0 += *(const f4*)(xp + (size_t)ss * D);
            s1 += *(const f4*)(xp + (size_t)(ss + 1) * D);
            s2 += *(const f4*)(xp + (size_t)(ss + 2) * D);
            s3 += *(const f4*)(xp + (size_t)(ss + 3) * D);
        }
        const f4 s = (s0 + s1) + (s2 + s3);
        *(f4*)&p_sh[d4 * 4] = s * 0.015625f;
    }
    __syncthreads();

    const int nit = D >> 8;
    for (int h0 = wid * 8; h0 < 512; h0 += 32) {
        float s[8];
        #pragma unroll
        for (int k = 0; k < 8; ++k) s[k] = 0.f;
        for (int it = 0; it < nit; ++it) {
            const int d = it * 256 + lane * 4;
            const f4 p = *(const f4*)&p_sh[d];
            #pragma unroll
            for (int k = 0; k < 8; ++k) {
                const f4 w = *(const f4*)&w1[(size_t)(h0 + k) * D + d];
                s[k] = fmaf(w[0], p[0], fmaf(w[1], p[1],
                       fmaf(w[2], p[2], fmaf(w[3], p[3], s[k]))));
            }
        }
        #pragma unroll
        for (int k = 0; k < 8; ++k) {
            float v = s[k];
            #pragma unroll
            for (int m = 1; m < 64; m <<= 1) v += __shfl_xor(v, m, 64);
            if (lane == 0) h_sh[h0 + k] = fmaxf(v + b1[h0 + k], 0.f);
        }
    }
    __syncthreads();

    for (int h0 = wid * 8; h0 < 512; h0 += 32) {
        float s[8];
        #pragma unroll
        for (int k = 0; k < 8; ++k) s[k] = 0.f;
        for (int it = 0; it < 2; ++it) {
            const int d = it * 256 + lane * 4;
            const f4 p = *(const f4*)&h_sh[d];
            #pragma unroll
            for (int k = 0; k < 8; ++k) {
                const f4 w = *(const f4*)&w2[(size_t)(h0 + k) * 512 + d];
                s[k] = fmaf(w[0], p[0], fmaf(w[1], p[1],
                       fmaf(w[2], p[2], fmaf(w[3], p[3], s[k]))));
            }
        }
        #pragma unroll
        for (int k = 0; k < 8; ++k) {
            float v = s[k];
            #pragma unroll
            for (int m = 1; m < 64; m <<= 1) v += __shfl_xor(v, m, 64);
            if (lane == 0) outT[(h0 + k) * 64 + bt] = v + b2[h0 + k];
        }
    }
    if (tid == 0) outT[512 * 64 + bt] = 1.0f;
}

// ---------------------------------------------------------------------------
// Kernel 2: bilinear h[bt,o] = relu( a^T W_o b + fb1[o] ).
// Grid 1024 x 512 thr; one block per o. Wave = bt-octet; thread e-set
// {4*lane..+3} U {256+4*lane..+3}; acc[8e][8bt] in VGPRs (verified R5).
// NEW: 4-deep LDS ring staged by async global_load_lds (width 16), one raw
// s_barrier + counted s_waitcnt vmcnt(6) per chunk (never drains to 0).
// Epoch c concurrency: compute(c) on buf[c&3], DMA into buf[(c+3)&3] --
// distinct mod 4 => race-free. Chunks at c=62/63 wrap (redundant, unread).
// ---------------------------------------------------------------------------
__global__ __launch_bounds__(512, 2) void bilinear_kernel(
    const float* __restrict__ fw1,  // (1024, 263169)
    const float* __restrict__ fb1,  // (1024)
    const float* __restrict__ aT,   // (513, 64)
    const float* __restrict__ bT,   // (513, 64)
    float* __restrict__ hbuf)       // (64, 1024)
{
    __shared__ float wbuf[4][8 * 512];  // 64 KB
    __shared__ float abuf[4][512];      //  8 KB
    const int tid = threadIdx.x;
    const int lane = tid & 63, w = tid >> 6;
    const int o = blockIdx.x;
    const float* __restrict__ W = fw1 + (size_t)o * TD;
    const int e0 = lane * 4;   // quads at e0 and e0+256
    const int bt0 = w * 8;

    // chunk c_ = 8 W-rows (e 0..511) + 8 a-rows; 3 DMA instrs per thread
    const int srow = tid >> 7, scol = (tid & 127) * 4;
    #define STAGE(buf_, c_)                                                    \
        do {                                                                   \
            _Pragma("unroll")                                                  \
            for (int s_ = 0; s_ < 2; ++s_) {                                   \
                const int r_ = s_ * 4 + srow;                                  \
                __builtin_amdgcn_global_load_lds(                              \
                    (const GAS uint32_t*)(const void*)(W + (size_t)(c_) * 8 * AB + (size_t)r_ * AB + scol), \
                    (LAS uint32_t*)(void*)&wbuf[buf_][r_ * 512 + scol], 16, 0, 0); \
            }                                                                  \
            __builtin_amdgcn_global_load_lds(                                  \
                (const GAS uint32_t*)(const void*)(aT + (size_t)(c_) * 512 + tid), \
                (LAS uint32_t*)(void*)&abuf[buf_][tid], 4, 0, 0);              \
        } while (0)

    float acc[8][8];  // [e-sub][bt]
    #pragma unroll
    for (int i = 0; i < 8; ++i)
        #pragma unroll
        for (int j = 0; j < 8; ++j) acc[i][j] = 0.f;

    STAGE(0, 0);
    STAGE(1, 1);

    #pragma unroll 1
    for (int c = 0; c < 64; ++c) {
        const int nc = (c + 2) & 63;   // wrap at 62/63: redundant, never read
        STAGE((c + 2) & 3, nc);
        asm volatile("s_waitcnt vmcnt(6)" ::: "memory");
        __builtin_amdgcn_s_barrier();
        asm volatile("" ::: "memory");

        const float* __restrict__ wb = wbuf[c & 3];
        const float* __restrict__ ab = abuf[c & 3];
        #pragma unroll
        for (int dd = 0; dd < 8; ++dd) {
            const f4 w0 = *(const f4*)&wb[dd * 512 + e0];
            const f4 w1v = *(const f4*)&wb[dd * 512 + e0 + 256];
            const f4 a0 = *(const f4*)&ab[dd * 64 + bt0];       // broadcast
            const f4 a1 = *(const f4*)&ab[dd * 64 + bt0 + 4];   // broadcast
            #pragma unroll
            for (int j = 0; j < 4; ++j) {
                #pragma unroll
                for (int i = 0; i < 4; ++i) {
                    acc[i][j]         = fmaf(w0[i],  a0[j], acc[i][j]);
                    acc[i + 4][j]     = fmaf(w1v[i], a0[j], acc[i + 4][j]);
                    acc[i][j + 4]     = fmaf(w0[i],  a1[j], acc[i][j + 4]);
                    acc[i + 4][j + 4] = fmaf(w1v[i], a1[j], acc[i + 4][j + 4]);
                }
            }
        }
    }

    // d = 512 row (a == 1): acc[i][*] += W[512, e_i]
    {
        const f4 r0 = *(const f4*)(W + (size_t)512 * AB + e0);
        const f4 r1 = *(const f4*)(W + (size_t)512 * AB + e0 + 256);
        #pragma unroll
        for (int j = 0; j < 8; ++j)
            #pragma unroll
            for (int i = 0; i < 4; ++i) {
                acc[i][j] += r0[i];
                acc[i + 4][j] += r1[i];
            }
    }

    // y[j] = sum over this thread's e of acc * b[e, bt0+j]
    float y[8];
    #pragma unroll
    for (int j = 0; j < 8; ++j) y[j] = 0.f;
    #pragma unroll
    for (int i = 0; i < 4; ++i) {
        const float* br0 = bT + (size_t)(e0 + i) * 64 + bt0;
        const float* br1 = bT + (size_t)(256 + e0 + i) * 64 + bt0;
        const f4 b0a = *(const f4*)br0, b0b = *(const f4*)(br0 + 4);
        const f4 b1a = *(const f4*)br1, b1b = *(const f4*)(br1 + 4);
        #pragma unroll
        for (int j = 0; j < 4; ++j) {
            y[j]     = fmaf(acc[i][j],     b0a[j], y[j]);
            y[j]     = fmaf(acc[i + 4][j], b1a[j], y[j]);
            y[j + 4] = fmaf(acc[i][j + 4],     b0b[j], y[j + 4]);
            y[j + 4] = fmaf(acc[i + 4][j + 4], b1b[j], y[j + 4]);
        }
    }

    // e = 512 column (b == 1): y[j] += sum_d a[d, bt0+j] * W[d, 512]
    #pragma unroll
    for (int k = 0; k < 8; ++k) {
        const int d = k * 64 + lane;
        const float wv = W[(size_t)d * AB + 512];
        const float* ar = aT + (size_t)d * 64 + bt0;
        const f4 a0 = *(const f4*)ar, a1 = *(const f4*)(ar + 4);
        #pragma unroll
        for (int j = 0; j < 4; ++j) {
            y[j]     = fmaf(a0[j], wv, y[j]);
            y[j + 4] = fmaf(a1[j], wv, y[j + 4]);
        }
    }
    {   // d = 512, e = 512 corner (a = b = 1), add on lane 0 only
        const float wc = (lane == 0) ? W[(size_t)512 * AB + 512] : 0.f;
        #pragma unroll
        for (int j = 0; j < 8; ++j) y[j] += wc;
    }

    // reduce across 64 lanes (all e), then bias + relu + store (per-wave)
    #pragma unroll
    for (int j = 0; j < 8; ++j) {
        float v = y[j];
        #pragma unroll
        for (int m = 1; m < 64; m <<= 1) v += __shfl_xor(v, m, 64);
        y[j] = v;
    }
    if (lane == 0) {
        const float bias = fb1[o];
        #pragma unroll
        for (int j = 0; j < 8; ++j)
            hbuf[(size_t)(bt0 + j) * 1024 + o] = fmaxf(y[j] + bias, 0.f);
    }
    #undef STAGE
}

// ---------------------------------------------------------------------------
// Kernel 3a: fused[bt, f] = h[bt, :] @ fw2[f, :] + fb2[f]
// ---------------------------------------------------------------------------
__global__ __launch_bounds__(256) void fuse2_kernel(
    const float* __restrict__ hbuf,  // (64, 1024)
    const float* __restrict__ fw2,   // (512, 1024)
    const float* __restrict__ fb2,   // (512)
    float* __restrict__ fused)       // (64, 512)
{
    __shared__ float h_sh[1024];
    const int bt = blockIdx.x, tid = threadIdx.x;
    const int lane = tid & 63, wid = tid >> 6;
    *(f4*)&h_sh[tid * 4] = *(const f4*)&hbuf[bt * 1024 + tid * 4];
    __syncthreads();
    for (int f0 = wid * 8; f0 < 512; f0 += 32) {
        float s[8];
        #pragma unroll
        for (int k = 0; k < 8; ++k) s[k] = 0.f;
        #pragma unroll
        for (int it = 0; it < 4; ++it) {
            const int d = it * 256 + lane * 4;
            const f4 p = *(const f4*)&h_sh[d];
            #pragma unroll
            for (int k = 0; k < 8; ++k) {
                const f4 w = *(const f4*)&fw2[(size_t)(f0 + k) * 1024 + d];
                s[k] = fmaf(w[0], p[0], fmaf(w[1], p[1],
                       fmaf(w[2], p[2], fmaf(w[3], p[3], s[k]))));
            }
        }
        #pragma unroll
        for (int k = 0; k < 8; ++k) {
            float v = s[k];
            #pragma unroll
            for (int m = 1; m < 64; m <<= 1) v += __shfl_xor(v, m, 64);
            if (lane == 0) fused[bt * 512 + f0 + k] = v + fb2[f0 + k];
        }
    }
}

// ---------------------------------------------------------------------------
// Kernel 3b: LIF over time. 1024 independent (b, d) chains, T = 32.
// ---------------------------------------------------------------------------
__global__ __launch_bounds__(256) void lif_kernel(
    const float* __restrict__ fused,  // (2, 32, 512)
    float* __restrict__ out)          // (2, 32, 512)
{
    const int idx = blockIdx.x * 256 + threadIdx.x;
    if (idx >= 1024) return;
    const int b = idx >> 9, dd = idx & 511;
    float mem = 0.f;
    for (int t = 0; t < 32; ++t) {
        const size_t off = ((size_t)(b * 32 + t) * 512) + dd;
        mem = 0.9f * mem + fused[off];
        const float s = (mem >= 1.0f) ? 1.0f : 0.0f;
        out[off] = s;
        mem -= s;
    }
}

// ---------------------------------------------------------------------------
extern "C" void kernel_launch(void* const* d_in, const int* in_sizes, int n_in,
                              void* d_out, int out_size, void* d_ws, size_t ws_size,
                              hipStream_t stream) {
    const float* vision = (const float*)d_in[0];
    const float* audio  = (const float*)d_in[1];
    const float* vw1 = (const float*)d_in[2];
    const float* vb1 = (const float*)d_in[3];
    const float* vw2 = (const float*)d_in[4];
    const float* vb2 = (const float*)d_in[5];
    const float* aw1 = (const float*)d_in[6];
    const float* ab1 = (const float*)d_in[7];
    const float* aw2 = (const float*)d_in[8];
    const float* ab2 = (const float*)d_in[9];
    const float* fw1 = (const float*)d_in[10];
    const float* fb1 = (const float*)d_in[11];
    const float* fw2 = (const float*)d_in[12];
    const float* fb2 = (const float*)d_in[13];
    float* out = (float*)d_out;

    float* ws    = (float*)d_ws;
    float* aT    = ws;                 // 513*64
    float* bT    = aT + AB * 64;       // 513*64
    float* hbuf  = bT + AB * 64;       // 64*1024
    float* fused = hbuf + 64 * 1024;   // 64*512

    unimodal_kernel<<<128, 256, 0, stream>>>(vision, audio,
        vw1, vb1, vw2, vb2, aw1, ab1, aw2, ab2, aT, bT);
    bilinear_kernel<<<1024, 512, 0, stream>>>(fw1, fb1, aT, bT, hbuf);
    fuse2_kernel<<<64, 256, 0, stream>>>(hbuf, fw2, fb2, fused);
    lif_kernel<<<4, 256, 0, stream>>>(fused, out);
}